// Round 5
// baseline (136.159 us; speedup 1.0000x reference)
//
#include <hip/hip_runtime.h>

typedef __fp16 f16;
typedef __fp16 f16x8 __attribute__((ext_vector_type(8)));
typedef __fp16 f16x4 __attribute__((ext_vector_type(4)));
typedef __fp16 f16x2 __attribute__((ext_vector_type(2)));
typedef float f32x4 __attribute__((ext_vector_type(4)));
typedef float f32x16 __attribute__((ext_vector_type(16)));

#define D_MODEL 1024
#define SEQ 2048
#define NH 16
#define MTOT 4096  // B*S

typedef const __attribute__((address_space(1))) unsigned int* gp1_t;
typedef __attribute__((address_space(3))) unsigned int* lp3_t;

__device__ __forceinline__ void gload_lds16(const void* g, void* l) {
  __builtin_amdgcn_global_load_lds((gp1_t)g, (lp3_t)l, 16, 0, 0);
}

// Z-row r' -> AO superrow j (the reference's transpose/view bug, closed form)
__device__ __forceinline__ int permrow(int r) {
  int bp = r >> 11, u = (r >> 7) & 15, t = r & 127;
  int g16 = (bp << 4) | u;
  return ((((g16 & 1) << 4) | (g16 >> 1)) << 7) + t;  // (b*16+h)*128 + t
}

__device__ __forceinline__ unsigned int pkrtz(float a, float b) {
  union { f16x2 h; unsigned int u; } z;
  z.h = __builtin_amdgcn_cvt_pkrtz(a, b);
  return z.u;
}

// ---------------- merged converts: qkv fp32->f16 (blocks 0..6143), wT (blocks 6144..7167) ----------------
__global__ __launch_bounds__(256) void cvt_all(const float* __restrict__ q,
                                               const float* __restrict__ k,
                                               const float* __restrict__ v,
                                               const float* __restrict__ wq,
                                               const float* __restrict__ wk,
                                               const float* __restrict__ wv,
                                               const float* __restrict__ wo,
                                               f16* __restrict__ qkv16,
                                               f16* __restrict__ wT) {
  __shared__ float tl[64][65];
  int bid = blockIdx.x, tid = threadIdx.x;
  if (bid < 6144) {
    int i = bid * 256 + tid;
    const int NT = (MTOT * D_MODEL) / 8;
    const float* src;
    int t;
    if (i < NT) { src = q; t = i; }
    else if (i < 2 * NT) { src = k; t = i - NT; }
    else { src = v; t = i - 2 * NT; }
    const float4* s4 = (const float4*)src;
    float4 a = s4[2 * t], b = s4[2 * t + 1];
    f16x8 h;
    h[0] = (f16)a.x; h[1] = (f16)a.y; h[2] = (f16)a.z; h[3] = (f16)a.w;
    h[4] = (f16)b.x; h[5] = (f16)b.y; h[6] = (f16)b.z; h[7] = (f16)b.w;
    *(f16x8*)(qkv16 + (size_t)i * 8) = h;
  } else {
    int bb = bid - 6144;
    int mat = bb >> 8, tile = bb & 255;
    int tk = (tile >> 4) << 6, tn = (tile & 15) << 6;
    const float* W = mat == 0 ? wq : mat == 1 ? wk : mat == 2 ? wv : wo;
    int rr = tid >> 4, c4 = (tid & 15) << 2;
#pragma unroll
    for (int it = 0; it < 4; ++it) {
      const float* p = W + (size_t)(tk + it * 16 + rr) * D_MODEL + tn + c4;
      float4 val = *(const float4*)p;
      tl[it * 16 + rr][c4 + 0] = val.x;
      tl[it * 16 + rr][c4 + 1] = val.y;
      tl[it * 16 + rr][c4 + 2] = val.z;
      tl[it * 16 + rr][c4 + 3] = val.w;
    }
    __syncthreads();
    int n = tid & 63, kseg = (tid >> 6) << 4;
    f16x8 lo, hi;
#pragma unroll
    for (int j = 0; j < 8; ++j) lo[j] = (f16)tl[kseg + j][n];
#pragma unroll
    for (int j = 0; j < 8; ++j) hi[j] = (f16)tl[kseg + 8 + j][n];
    f16* d = wT + (size_t)mat * (D_MODEL * D_MODEL) + (size_t)(tn + n) * D_MODEL + tk + kseg;
    *(f16x8*)d = lo;
    *(f16x8*)(d + 8) = hi;
  }
}

// ---------------- fused QKV projection GEMM v4: 256x256 tile, 4 waves of 128x128 ----------------
// LDS-BW-bound regime (v1/v2/v3 all collapse onto CUs x FLOP-per-LDS-byte = const).
// Raise FLOP/B: per-wave tile 128x128 -> Mw*Nw/(Mw+Nw) = 64 (was 42.7). 256 threads,
// acc f32x4[8][8] = 256 VGPR, launch_bounds(256,1) (1 wave/SIMD, 512-VGPR budget).
// Keep v3's verified 4-slot ring + 3-deep prefetch + counted vmcnt + swizzle exactly.
// Per iter: vmcnt(16) -> s_barrier -> stage t+3 (8 loads/thread) -> 16x ds_read_b128 ->
// lgkmcnt(0) -> 64 MFMA.
#define SLOT_ELEM 16384  // 32 KB in f16
__global__ __launch_bounds__(256, 1) void gemm_qkv(const f16* __restrict__ q16,
                                                   const f16* __restrict__ k16,
                                                   const f16* __restrict__ v16,
                                                   const f16* __restrict__ wT,
                                                   const float* __restrict__ bq,
                                                   const float* __restrict__ bk,
                                                   const float* __restrict__ bv,
                                                   f16* __restrict__ Q16,
                                                   f16* __restrict__ K16,
                                                   f16* __restrict__ VT16) {
  extern __shared__ __attribute__((aligned(16))) f16 sm[];  // 4 x 32 KB ring
  const int K = D_MODEL, N = D_MODEL;
  const size_t WEL = (size_t)D_MODEL * D_MODEL;
  int z = blockIdx.z;
  const f16* A = z == 0 ? q16 : z == 1 ? k16 : v16;
  const f16* BT = wT + (size_t)z * WEL;
  const float* bias = z == 0 ? bq : z == 1 ? bk : bv;

  int tid = threadIdx.x;
  int w = tid >> 6, lane = tid & 63;
  int g = lane >> 4, c = lane & 15;
  int wr = w >> 1, wc = w & 1;
  int m0 = blockIdx.x * 256, n0 = blockIdx.y * 256;
  f32x4 acc[8][8] = {};

  // ---- staging geometry: wave w stages rows w*64..w*64+63 of A and B (4 loads each).
  // Each gload covers 16 rows (64 lanes x 16 B = 1 KB, rows are 64 B).
  // LDS-linear within chunk: lane l -> superrow sl0 = l>>3, slot s = l&7.
  // Inverse swizzle: u = s ^ (sl0&7); row-low = u>>2, col16 = u&3.
  int sl0 = lane >> 3, s = lane & 7;
  int u = s ^ sl0;
  int rlow = u >> 2, gsl = u & 3;
  const f16* Agp = A + (size_t)(m0 + w * 64 + 2 * sl0 + rlow) * K + gsl * 8;
  const f16* Bgp = BT + (size_t)(n0 + w * 64 + 2 * sl0 + rlow) * K + gsl * 8;

#define STAGE_QKV(tt, bi)                                                    \
  {                                                                          \
    f16* dA = sm + (bi)*SLOT_ELEM + w * 2048;                                \
    f16* dB = dA + 8192;                                                     \
    const f16* sa = Agp + (size_t)(tt)*32;                                   \
    const f16* sb = Bgp + (size_t)(tt)*32;                                   \
    gload_lds16(sa, dA);                                                     \
    gload_lds16(sa + (size_t)16 * K, dA + 512);                              \
    gload_lds16(sa + (size_t)32 * K, dA + 1024);                             \
    gload_lds16(sa + (size_t)48 * K, dA + 1536);                             \
    gload_lds16(sb, dB);                                                     \
    gload_lds16(sb + (size_t)16 * K, dB + 512);                              \
    gload_lds16(sb + (size_t)32 * K, dB + 1024);                             \
    gload_lds16(sb + (size_t)48 * K, dB + 1536);                             \
  }

  // prologue: stage tiles 0,1,2 into slots 0,1,2 (24 loads/thread in flight)
  STAGE_QKV(0, 0)
  STAGE_QKV(1, 1)
  STAGE_QKV(2, 2)

  const int NKT = K / 32;  // 32
  for (int t = 0; t < NKT; ++t) {
    if (t < NKT - 2) asm volatile("s_waitcnt vmcnt(16)" ::: "memory");
    else if (t == NKT - 2) asm volatile("s_waitcnt vmcnt(8)" ::: "memory");
    else asm volatile("s_waitcnt vmcnt(0)" ::: "memory");
    __builtin_amdgcn_sched_barrier(0);
    __builtin_amdgcn_s_barrier();  // tile t resident; all reads of slot (t+3)&3 (tile t-1) drained
    __builtin_amdgcn_sched_barrier(0);
    if (t + 3 < NKT) STAGE_QKV(t + 3, (t + 3) & 3)

    const char* Ac = (const char*)(sm + (t & 3) * SLOT_ELEM);
    const char* Bc = Ac + 16384;  // bytes
    f16x8 af[8], bf[8];
#pragma unroll
    for (int mi = 0; mi < 8; ++mi) {
      int row = wr * 128 + mi * 16 + c;
      int tb = (row >> 1) * 128 + (((((row & 1) << 2) | g) ^ ((row >> 1) & 7)) << 4);
      af[mi] = *(const f16x8*)(Ac + tb);
    }
#pragma unroll
    for (int ni = 0; ni < 8; ++ni) {
      int row = wc * 128 + ni * 16 + c;
      int tb = (row >> 1) * 128 + (((((row & 1) << 2) | g) ^ ((row >> 1) & 7)) << 4);
      bf[ni] = *(const f16x8*)(Bc + tb);
    }
    asm volatile("s_waitcnt lgkmcnt(0)" ::: "memory");
    __builtin_amdgcn_sched_barrier(0);
    __builtin_amdgcn_s_setprio(1);
#pragma unroll
    for (int mi = 0; mi < 8; ++mi)
#pragma unroll
      for (int ni = 0; ni < 8; ++ni)
        acc[mi][ni] = __builtin_amdgcn_mfma_f32_16x16x32_f16(af[mi], bf[ni], acc[mi][ni], 0, 0, 0);
    __builtin_amdgcn_s_setprio(0);
  }

  int rb = m0 + wr * 128;
  int cb = n0 + wc * 128;
  if (z < 2) {
    f16* O = z == 0 ? Q16 : K16;
#pragma unroll
    for (int m = 0; m < 8; ++m) {
      int row0 = rb + m * 16 + 4 * g;
#pragma unroll
      for (int n = 0; n < 8; ++n) {
        int col = cb + n * 16 + c;
        float bv2 = bias[col];
#pragma unroll
        for (int r = 0; r < 4; ++r) O[(size_t)(row0 + r) * N + col] = (f16)(acc[m][n][r] + bv2);
      }
    }
  } else {
    f16* O = VT16;
#pragma unroll
    for (int m = 0; m < 8; ++m) {
      int s0f = rb + m * 16 + 4 * g;
      int bb = s0f >> 11, ss = s0f & (SEQ - 1);
#pragma unroll
      for (int n = 0; n < 8; ++n) {
        int col = cb + n * 16 + c;
        float bv2 = bias[col];
        f16x4 hv;
#pragma unroll
        for (int r = 0; r < 4; ++r) hv[r] = (f16)(acc[m][n][r] + bv2);
        *(f16x4*)(O + ((size_t)(bb * NH + (col >> 6)) * 64 + (col & 63)) * SEQ + ss) = hv;
      }
    }
  }
}

// ---------------- O-projection GEMM: 64x128 tiles, permuted A rows, f32 out ----------------
__global__ __launch_bounds__(256, 2) void gemm_out(const f16* __restrict__ A,
                                                   const f16* __restrict__ BT,
                                                   const float* __restrict__ bias,
                                                   float* __restrict__ O) {
  const int K = D_MODEL, N = D_MODEL;
  __shared__ f16 As[64 * 64];
  __shared__ f16 Bs[128 * 64];
  int tid = threadIdx.x;
  int w = tid >> 6, lane = tid & 63;
  int g = lane >> 4, c = lane & 15;
  int wr = w >> 1, wc = w & 1;
  int m0 = blockIdx.x * 64, n0 = blockIdx.y * 128;
  f32x4 acc[2][4] = {};

  for (int kt = 0; kt < K; kt += 64) {
#pragma unroll
    for (int i = 0; i < 2; ++i) {
      int seg = w * 2 + i;
      int p = seg * 1024 + lane * 16;
      int row = p >> 7;
      int colb = (p & 127) ^ ((row & 7) << 4);
      int ae = kt + (colb >> 1);
      gload_lds16(A + (size_t)permrow(m0 + row) * K + ae, &As[seg * 512]);
    }
#pragma unroll
    for (int i = 0; i < 4; ++i) {
      int seg = w * 4 + i;
      int p = seg * 1024 + lane * 16;
      int row = p >> 7;
      int colb = (p & 127) ^ ((row & 7) << 4);
      int ae = kt + (colb >> 1);
      gload_lds16(BT + (size_t)(n0 + row) * K + ae, &Bs[seg * 512]);
    }
    __syncthreads();
    f16x8 af[2][2], bf[4][2];
#pragma unroll
    for (int m = 0; m < 2; ++m) {
#pragma unroll
      for (int kk = 0; kk < 2; ++kk) {
        int row = wr * 32 + m * 16 + c;
        int tb = (row * 128 + kk * 64 + g * 16) ^ ((row & 7) << 4);
        af[m][kk] = *(const f16x8*)((const char*)As + tb);
      }
    }
#pragma unroll
    for (int n = 0; n < 4; ++n) {
#pragma unroll
      for (int kk = 0; kk < 2; ++kk) {
        int row = wc * 64 + n * 16 + c;
        int tb = (row * 128 + kk * 64 + g * 16) ^ ((row & 7) << 4);
        bf[n][kk] = *(const f16x8*)((const char*)Bs + tb);
      }
    }
    __builtin_amdgcn_s_setprio(1);
#pragma unroll
    for (int m = 0; m < 2; ++m)
#pragma unroll
      for (int n = 0; n < 4; ++n)
#pragma unroll
        for (int kk = 0; kk < 2; ++kk)
          acc[m][n] = __builtin_amdgcn_mfma_f32_16x16x32_f16(af[m][kk], bf[n][kk], acc[m][n], 0, 0, 0);
    __builtin_amdgcn_s_setprio(0);
    __syncthreads();
  }

  int rb = m0 + wr * 32;
  int cb = n0 + wc * 64;
#pragma unroll
  for (int m = 0; m < 2; ++m) {
    int row0 = rb + m * 16 + 4 * g;
#pragma unroll
    for (int n = 0; n < 4; ++n) {
      int col = cb + n * 16 + c;
      float bv = bias[col];
#pragma unroll
      for (int r = 0; r < 4; ++r) O[(size_t)(row0 + r) * N + col] = acc[m][n][r] + bv;
    }
  }
}

// ---------------- causal flash attention v7: kv-parity split + flash merge ----------------
#define THR2 11.5f  // defer-max threshold, log2 domain
__global__ __launch_bounds__(256, 2) void attn_kernel(const f16* __restrict__ Q,
                                                      const f16* __restrict__ K,
                                                      const f16* __restrict__ VT,
                                                      f16* __restrict__ AO) {
  __shared__ __attribute__((aligned(16))) f16 Ksh[2][2][64 * 64];  // [buf][par] 32 KB
  __shared__ __attribute__((aligned(16))) f16 Vsh[2][2][64 * 64];  // 32 KB
  const int BUFO = 2 * 64 * 64;  // f16 elems between buf0/buf1
  int tid = threadIdx.x;
  int w = tid >> 6, lane = tid & 63;
  int c = lane & 31, hi = lane >> 5;
  int qh = w & 1, par = w >> 1;
  int blk = blockIdx.x;
  int bh = blk & 31;        // low bits -> head pinned per XCD
  int uu = blk >> 5;
  int cb = 31 - uu;         // big chunks first -> backfill-friendly schedule
  int b = bh >> 4, h = bh & 15;
  int q0 = cb * 64 + qh * 32;
  const int NT = cb + 1;
  const size_t brow = (size_t)b * SEQ;
  const int hcol = h * 64;

  // staging geometry: wave (qh,par) stages tile (t0+par), rows qh*32 + j*8 + (lane>>3)
  int sr = lane >> 3;
  int seo = ((lane & 7) ^ sr) << 3;
  const f16* Kgb = K + (size_t)(brow + qh * 32 + sr) * D_MODEL + hcol + seo;  // + kv*D_MODEL
  const f16* Vgb = VT + ((size_t)bh * 64 + qh * 32 + sr) * SEQ + seo;         // + kv
  f16* Kshf = &Ksh[0][0][0];
  f16* Vshf = &Vsh[0][0][0];
  f16* KshW = Kshf + par * 4096 + qh * 32 * 64;
  f16* VshW = Vshf + par * 4096 + qh * 32 * 64;

  // Q B-fragments (col=q-row=c, k = 16*kk + 8*hi + j), pre-scaled by log2e
  const f16 LOG2E = (f16)1.44269504f;
  f16x8 qf[4];
  const f16* Qp = Q + (size_t)(brow + q0 + c) * D_MODEL + hcol + 8 * hi;
#pragma unroll
  for (int kk = 0; kk < 4; ++kk) {
    qf[kk] = *(const f16x8*)(Qp + 16 * kk);
#pragma unroll
    for (int j = 0; j < 8; ++j) qf[kk][j] = (f16)(qf[kk][j] * LOG2E);
  }

  float m_st = -1e30f, l_st = 0.f;
  f32x16 o0 = {}, o1 = {};  // O^T accumulators, d-tiles 0..31 / 32..63; col=q per lane

  // prologue: stage pair {0,1} into buf 0 (this wave: tile par, if it exists)
  if (par < NT) {
    int kv = par * 64;
#pragma unroll
    for (int j = 0; j < 4; ++j) {
      gload_lds16(Kgb + (size_t)(kv + j * 8) * D_MODEL, KshW + (j * 8) * 64);
      gload_lds16(Vgb + (size_t)(j * 8) * SEQ + kv, VshW + (j * 8) * 64);
    }
  }
  __syncthreads();

  int rsw = (c & 7) << 4;
  int cur = 0;
  const int U = (NT + 1) >> 1;
  for (int u = 0; u < U; ++u) {
    int tpre = 2 * u + 2 + par;
    if (tpre < NT) {
      int kv = tpre * 64;
      f16* kd = KshW + (cur ^ 1) * BUFO;
      f16* vd = VshW + (cur ^ 1) * BUFO;
#pragma unroll
      for (int j = 0; j < 4; ++j) {
        gload_lds16(Kgb + (size_t)(kv + j * 8) * D_MODEL, kd + (j * 8) * 64);
        gload_lds16(Vgb + (size_t)(j * 8) * SEQ + kv, vd + (j * 8) * 64);
      }
    }
    int t = 2 * u + par;
    if (t < NT) {
      const char* Kb = (const char*)(Kshf + cur * BUFO + par * 4096);
      const char* Vb = (const char*)(Vshf + cur * BUFO + par * 4096);
      // ---- QK^T swapped: S^T[kv][q] = K . Q^T ----
      f16x8 kf[2][4];
#pragma unroll
      for (int ks = 0; ks < 2; ++ks)
#pragma unroll
        for (int kk = 0; kk < 4; ++kk)
          kf[ks][kk] = *(const f16x8*)(Kb + (((ks * 32 + c) * 128 + 32 * kk + 16 * hi) ^ rsw));
      f32x16 s0 = {}, s1 = {};
      __builtin_amdgcn_s_setprio(1);
#pragma unroll
      for (int kk = 0; kk < 4; ++kk) {
        s0 = __builtin_amdgcn_mfma_f32_32x32x16_f16(kf[0][kk], qf[kk], s0, 0, 0, 0);
        s1 = __builtin_amdgcn_mfma_f32_32x32x16_f16(kf[1][kk], qf[kk], s1, 0, 0, 0);
      }
      __builtin_amdgcn_s_setprio(0);
      // hoist V reads: independent of softmax, covers ds latency under VALU
      f16x8 vf[2][4];
#pragma unroll
      for (int dt = 0; dt < 2; ++dt)
#pragma unroll
        for (int kk = 0; kk < 4; ++kk)
          vf[dt][kk] = *(const f16x8*)(Vb + (((dt * 32 + c) * 128 + 32 * kk + 16 * hi) ^ rsw));
      // ---- causal mask (diagonal tile only); kv = 64t + 32ks + (r&3)+8(r>>2)+4hi ----
      if (t == NT - 1) {
        int q = q0 + c;
        int kvb = t * 64 + 4 * hi;
#pragma unroll
        for (int r = 0; r < 16; ++r) {
          int kv = kvb + (r & 3) + 8 * (r >> 2);
          if (kv > q) s0[r] = -1e30f;
          if (kv + 32 > q) s1[r] = -1e30f;
        }
      }
      // ---- online softmax: each lane holds 32 scores of ONE q-row (other half at lane^32) ----
      float t8[8];
#pragma unroll
      for (int r = 0; r < 8; ++r)
        t8[r] = fmaxf(fmaxf(s0[r], s0[r + 8]), fmaxf(s1[r], s1[r + 8]));
      float pm = fmaxf(fmaxf(fmaxf(t8[0], t8[1]), fmaxf(t8[2], t8[3])),
                       fmaxf(fmaxf(t8[4], t8[5]), fmaxf(t8[6], t8[7])));
      float mx = fmaxf(pm, __shfl_xor(pm, 32));
      if (__any(mx > m_st + THR2)) {
        float mnew = fmaxf(m_st, mx);
        float corr = __builtin_amdgcn_exp2f(m_st - mnew);
        l_st *= corr;
#pragma unroll
        for (int r = 0; r < 16; ++r) { o0[r] *= corr; o1[r] *= corr; }
        m_st = mnew;
      }
      float ts[16];
#pragma unroll
      for (int r = 0; r < 16; ++r) {
        float p0 = __builtin_amdgcn_exp2f(s0[r] - m_st);  // <= 2^11.5, f16-safe
        float p1 = __builtin_amdgcn_exp2f(s1[r] - m_st);
        s0[r] = p0; s1[r] = p1;
        ts[r] = p0 + p1;
      }
#pragma unroll
      for (int st = 8; st > 0; st >>= 1)
#pragma unroll
        for (int r = 0; r < st; ++r) ts[r] += ts[r + st];
      l_st += ts[0];
      // ---- P -> PV B-fragments in-register (cvt_pkrtz pairs + permlane32 hi/lo swap) ----
      union PU { unsigned int u[4]; f16x8 v; };
      PU pu[4];
#pragma unroll
      for (int kk = 0; kk < 4; ++kk) {
        int rb = 8 * (kk & 1);
        unsigned int la0, la1, lb0, lb1;
        if (kk < 2) {
          la0 = pkrtz(s0[rb + 0], s0[rb + 1]);
          la1 = pkrtz(s0[rb + 2], s0[rb + 3]);
          lb0 = pkrtz(s0[rb + 4], s0[rb + 5]);
          lb1 = pkrtz(s0[rb + 6], s0[rb + 7]);
        } else {
          la0 = pkrtz(s1[rb + 0], s1[rb + 1]);
          la1 = pkrtz(s1[rb + 2], s1[rb + 3]);
          lb0 = pkrtz(s1[rb + 4], s1[rb + 5]);
          lb1 = pkrtz(s1[rb + 6], s1[rb + 7]);
        }
        asm("v_permlane32_swap_b32 %0, %1" : "+v"(la0), "+v"(lb0));
        asm("v_permlane32_swap_b32 %0, %1" : "+v"(la1), "+v"(lb1));
        pu[kk].u[0] = la0; pu[kk].u[1] = la1; pu[kk].u[2] = lb0; pu[kk].u[3] = lb1;
      }
      // ---- PV: O^T[d][q] += V^T[d][kv] * P^T[kv][q] ----
      __builtin_amdgcn_s_setprio(1);
#pragma unroll
      for (int kk = 0; kk < 4; ++kk) {
        o0 = __builtin_amdgcn_mfma_f32_32x32x16_f16(vf[0][kk], pu[kk].v, o0, 0, 0, 0);
        o1 = __builtin_amdgcn_mfma_f32_32x32x16_f16(vf[1][kk], pu[kk].v, o1, 0, 0, 0);
      }
      __builtin_amdgcn_s_setprio(0);
    }
    __syncthreads();
    cur ^= 1;
  }

  // ---- flash merge of parity partials (exact): par1 publishes, par0 combines ----
  float* sc = (float*)Kshf;  // K LDS dead after loop; 128 x 34 f32 = 17 KB
  int mb = (qh * 64 + lane) * 34;
  if (par == 1) {
    sc[mb] = m_st;
    sc[mb + 1] = l_st;
#pragma unroll
    for (int r = 0; r < 16; ++r) { sc[mb + 2 + r] = o0[r]; sc[mb + 18 + r] = o1[r]; }
  }
  __syncthreads();
  if (par == 0) {
    float m1 = sc[mb], l1 = sc[mb + 1];
    float mm = fmaxf(m_st, m1);
    float c0 = __builtin_amdgcn_exp2f(m_st - mm);
    float c1 = __builtin_amdgcn_exp2f(m1 - mm);
    float l = l_st * c0 + l1 * c1;
#pragma unroll
    for (int r = 0; r < 16; ++r) {
      o0[r] = o0[r] * c0 + sc[mb + 2 + r] * c1;
      o1[r] = o1[r] * c0 + sc[mb + 18 + r] * c1;
    }
    // combine hi/lo kv-half row sums, normalize, write AO[bh][s][64]
    float lt = l + __shfl_xor(l, 32);
    float linv = 1.0f / lt;
    f16* aoq = AO + ((size_t)bh * SEQ + q0 + c) * 64 + 4 * hi;
#pragma unroll
    for (int rq = 0; rq < 4; ++rq) {
      f16x4 h0, h1;
#pragma unroll
      for (int r = 0; r < 4; ++r) {
        h0[r] = (f16)(o0[4 * rq + r] * linv);
        h1[r] = (f16)(o1[4 * rq + r] * linv);
      }
      *(f16x4*)(aoq + 8 * rq) = h0;
      *(f16x4*)(aoq + 32 + 8 * rq) = h1;
    }
  }
}

extern "C" void kernel_launch(void* const* d_in, const int* in_sizes, int n_in,
                              void* d_out, int out_size, void* d_ws, size_t ws_size,
                              hipStream_t stream) {
  const float* q  = (const float*)d_in[0];
  const float* k  = (const float*)d_in[1];
  const float* v  = (const float*)d_in[2];
  const float* wq = (const float*)d_in[3];
  const float* bq = (const float*)d_in[4];
  const float* wk = (const float*)d_in[5];
  const float* bk = (const float*)d_in[6];
  const float* wv = (const float*)d_in[7];
  const float* bv = (const float*)d_in[8];
  const float* wo = (const float*)d_in[9];
  const float* bo = (const float*)d_in[10];

  const size_t TEN = (size_t)MTOT * D_MODEL;
  const size_t WEL = (size_t)D_MODEL * D_MODEL;
  f16* ws  = (f16*)d_ws;
  f16* q16 = ws;
  f16* k16 = q16 + TEN;
  f16* v16 = k16 + TEN;
  f16* wT  = v16 + TEN;
  f16* Q16 = wT + 4 * WEL;
  f16* K16 = Q16 + TEN;
  f16* VT16 = K16 + TEN;
  f16* AO  = q16;  // alias: q16 dead after QKV projection

  static bool attr_set = false;
  if (!attr_set) {
    hipFuncSetAttribute(reinterpret_cast<const void*>(&gemm_qkv),
                        hipFuncAttributeMaxDynamicSharedMemorySize, 131072);
    attr_set = true;
  }

  cvt_all<<<7168, 256, 0, stream>>>(q, k, v, wq, wk, wv, wo, q16, wT);
  gemm_qkv<<<dim3(16, 4, 3), 256, 131072, stream>>>(q16, k16, v16, wT, bq, bk, bv, Q16, K16, VT16);
  attn_kernel<<<1024, 256, 0, stream>>>(Q16, K16, VT16, AO);
  gemm_out<<<dim3(64, 8), 256, 0, stream>>>(AO, wT + 3 * WEL, bo, (float*)d_out);
}

// Round 6
// 123.908 us; speedup vs baseline: 1.0989x; 1.0989x over previous
//
#include <hip/hip_runtime.h>

typedef __fp16 f16;
typedef __fp16 f16x8 __attribute__((ext_vector_type(8)));
typedef __fp16 f16x4 __attribute__((ext_vector_type(4)));
typedef __fp16 f16x2 __attribute__((ext_vector_type(2)));
typedef float f32x4 __attribute__((ext_vector_type(4)));
typedef float f32x16 __attribute__((ext_vector_type(16)));

#define D_MODEL 1024
#define SEQ 2048
#define NH 16
#define MTOT 4096  // B*S

typedef const __attribute__((address_space(1))) unsigned int* gp1_t;
typedef __attribute__((address_space(3))) unsigned int* lp3_t;

__device__ __forceinline__ void gload_lds16(const void* g, void* l) {
  __builtin_amdgcn_global_load_lds((gp1_t)g, (lp3_t)l, 16, 0, 0);
}

// Z-row r' -> AO superrow j (the reference's transpose/view bug, closed form)
__device__ __forceinline__ int permrow(int r) {
  int bp = r >> 11, u = (r >> 7) & 15, t = r & 127;
  int g16 = (bp << 4) | u;
  return ((((g16 & 1) << 4) | (g16 >> 1)) << 7) + t;  // (b*16+h)*128 + t
}

__device__ __forceinline__ unsigned int pkrtz(float a, float b) {
  union { f16x2 h; unsigned int u; } z;
  z.h = __builtin_amdgcn_cvt_pkrtz(a, b);
  return z.u;
}

// ---------------- merged converts: qkv fp32->f16 (blocks 0..6143), wT (blocks 6144..7167) ----------------
__global__ __launch_bounds__(256) void cvt_all(const float* __restrict__ q,
                                               const float* __restrict__ k,
                                               const float* __restrict__ v,
                                               const float* __restrict__ wq,
                                               const float* __restrict__ wk,
                                               const float* __restrict__ wv,
                                               const float* __restrict__ wo,
                                               f16* __restrict__ qkv16,
                                               f16* __restrict__ wT) {
  __shared__ float tl[64][65];
  int bid = blockIdx.x, tid = threadIdx.x;
  if (bid < 6144) {
    int i = bid * 256 + tid;
    const int NT = (MTOT * D_MODEL) / 8;
    const float* src;
    int t;
    if (i < NT) { src = q; t = i; }
    else if (i < 2 * NT) { src = k; t = i - NT; }
    else { src = v; t = i - 2 * NT; }
    const float4* s4 = (const float4*)src;
    float4 a = s4[2 * t], b = s4[2 * t + 1];
    f16x8 h;
    h[0] = (f16)a.x; h[1] = (f16)a.y; h[2] = (f16)a.z; h[3] = (f16)a.w;
    h[4] = (f16)b.x; h[5] = (f16)b.y; h[6] = (f16)b.z; h[7] = (f16)b.w;
    *(f16x8*)(qkv16 + (size_t)i * 8) = h;
  } else {
    int bb = bid - 6144;
    int mat = bb >> 8, tile = bb & 255;
    int tk = (tile >> 4) << 6, tn = (tile & 15) << 6;
    const float* W = mat == 0 ? wq : mat == 1 ? wk : mat == 2 ? wv : wo;
    int rr = tid >> 4, c4 = (tid & 15) << 2;
#pragma unroll
    for (int it = 0; it < 4; ++it) {
      const float* p = W + (size_t)(tk + it * 16 + rr) * D_MODEL + tn + c4;
      float4 val = *(const float4*)p;
      tl[it * 16 + rr][c4 + 0] = val.x;
      tl[it * 16 + rr][c4 + 1] = val.y;
      tl[it * 16 + rr][c4 + 2] = val.z;
      tl[it * 16 + rr][c4 + 3] = val.w;
    }
    __syncthreads();
    int n = tid & 63, kseg = (tid >> 6) << 4;
    f16x8 lo, hi;
#pragma unroll
    for (int j = 0; j < 8; ++j) lo[j] = (f16)tl[kseg + j][n];
#pragma unroll
    for (int j = 0; j < 8; ++j) hi[j] = (f16)tl[kseg + 8 + j][n];
    f16* d = wT + (size_t)mat * (D_MODEL * D_MODEL) + (size_t)(tn + n) * D_MODEL + tk + kseg;
    *(f16x8*)d = lo;
    *(f16x8*)(d + 8) = hi;
  }
}

// ---------------- fused QKV projection GEMM v3 (reverted, verified ~41 us):
// 256x256 tile, BK=32, 4-slot LDS ring, 3-tile-deep prefetch, counted vmcnt.
// 8 waves (512 thr), 1 block/CU, grid (16,4,3).
#define SLOT_ELEM 16384  // 32 KB in f16
__global__ __launch_bounds__(512, 2) void gemm_qkv(const f16* __restrict__ q16,
                                                   const f16* __restrict__ k16,
                                                   const f16* __restrict__ v16,
                                                   const f16* __restrict__ wT,
                                                   const float* __restrict__ bq,
                                                   const float* __restrict__ bk,
                                                   const float* __restrict__ bv,
                                                   f16* __restrict__ Q16,
                                                   f16* __restrict__ K16,
                                                   f16* __restrict__ VT16) {
  extern __shared__ __attribute__((aligned(16))) f16 sm[];  // 4 x 32 KB ring
  const int K = D_MODEL, N = D_MODEL;
  const size_t WEL = (size_t)D_MODEL * D_MODEL;
  int z = blockIdx.z;
  const f16* A = z == 0 ? q16 : z == 1 ? k16 : v16;
  const f16* BT = wT + (size_t)z * WEL;
  const float* bias = z == 0 ? bq : z == 1 ? bk : bv;

  int tid = threadIdx.x;
  int w = tid >> 6, lane = tid & 63;
  int g = lane >> 4, c = lane & 15;
  int wr = w >> 2, wc = w & 3;
  int m0 = blockIdx.x * 256, n0 = blockIdx.y * 256;
  f32x4 acc[8][4] = {};

  int sl0 = lane >> 3, s = lane & 7;
  int u = s ^ sl0;
  int rlow = u >> 2, gsl = u & 3;
  const f16* Agp = A + (size_t)(m0 + w * 32 + 2 * sl0 + rlow) * K + gsl * 8;
  const f16* Bgp = BT + (size_t)(n0 + w * 32 + 2 * sl0 + rlow) * K + gsl * 8;

#define STAGE_QKV(tt, bi)                                                    \
  {                                                                          \
    f16* dA = sm + (bi)*SLOT_ELEM + w * 1024;                                \
    f16* dB = dA + 8192;                                                     \
    const f16* sa = Agp + (size_t)(tt)*32;                                   \
    const f16* sb = Bgp + (size_t)(tt)*32;                                   \
    gload_lds16(sa, dA);                                                     \
    gload_lds16(sa + (size_t)16 * K, dA + 512);                              \
    gload_lds16(sb, dB);                                                     \
    gload_lds16(sb + (size_t)16 * K, dB + 512);                              \
  }

  STAGE_QKV(0, 0)
  STAGE_QKV(1, 1)
  STAGE_QKV(2, 2)

  const int NKT = K / 32;  // 32
  for (int t = 0; t < NKT; ++t) {
    if (t < NKT - 2) asm volatile("s_waitcnt vmcnt(8)" ::: "memory");
    else if (t == NKT - 2) asm volatile("s_waitcnt vmcnt(4)" ::: "memory");
    else asm volatile("s_waitcnt vmcnt(0)" ::: "memory");
    __builtin_amdgcn_sched_barrier(0);
    __builtin_amdgcn_s_barrier();
    __builtin_amdgcn_sched_barrier(0);
    if (t + 3 < NKT) STAGE_QKV(t + 3, (t + 3) & 3)

    const char* Ac = (const char*)(sm + (t & 3) * SLOT_ELEM);
    const char* Bc = Ac + 16384;  // bytes
    f16x8 af[8], bf[4];
#pragma unroll
    for (int mi = 0; mi < 8; ++mi) {
      int row = wr * 128 + mi * 16 + c;
      int tb = (row >> 1) * 128 + (((((row & 1) << 2) | g) ^ ((row >> 1) & 7)) << 4);
      af[mi] = *(const f16x8*)(Ac + tb);
    }
#pragma unroll
    for (int ni = 0; ni < 4; ++ni) {
      int row = wc * 64 + ni * 16 + c;
      int tb = (row >> 1) * 128 + (((((row & 1) << 2) | g) ^ ((row >> 1) & 7)) << 4);
      bf[ni] = *(const f16x8*)(Bc + tb);
    }
    asm volatile("s_waitcnt lgkmcnt(0)" ::: "memory");
    __builtin_amdgcn_sched_barrier(0);
    __builtin_amdgcn_s_setprio(1);
#pragma unroll
    for (int mi = 0; mi < 8; ++mi)
#pragma unroll
      for (int ni = 0; ni < 4; ++ni)
        acc[mi][ni] = __builtin_amdgcn_mfma_f32_16x16x32_f16(af[mi], bf[ni], acc[mi][ni], 0, 0, 0);
    __builtin_amdgcn_s_setprio(0);
  }

  int rb = m0 + wr * 128;
  int cb = n0 + wc * 64;
  if (z < 2) {
    f16* O = z == 0 ? Q16 : K16;
#pragma unroll
    for (int m = 0; m < 8; ++m) {
      int row0 = rb + m * 16 + 4 * g;
#pragma unroll
      for (int n = 0; n < 4; ++n) {
        int col = cb + n * 16 + c;
        float bv2 = bias[col];
#pragma unroll
        for (int r = 0; r < 4; ++r) O[(size_t)(row0 + r) * N + col] = (f16)(acc[m][n][r] + bv2);
      }
    }
  } else {
    f16* O = VT16;
#pragma unroll
    for (int m = 0; m < 8; ++m) {
      int s0f = rb + m * 16 + 4 * g;
      int bb = s0f >> 11, ss = s0f & (SEQ - 1);
#pragma unroll
      for (int n = 0; n < 4; ++n) {
        int col = cb + n * 16 + c;
        float bv2 = bias[col];
        f16x4 hv;
#pragma unroll
        for (int r = 0; r < 4; ++r) hv[r] = (f16)(acc[m][n][r] + bv2);
        *(f16x4*)(O + ((size_t)(bb * NH + (col >> 6)) * 64 + (col & 63)) * SEQ + ss) = hv;
      }
    }
  }
}

// ---------------- O-projection GEMM: 64x128 tiles, permuted A rows, f32 out ----------------
__global__ __launch_bounds__(256, 2) void gemm_out(const f16* __restrict__ A,
                                                   const f16* __restrict__ BT,
                                                   const float* __restrict__ bias,
                                                   float* __restrict__ O) {
  const int K = D_MODEL, N = D_MODEL;
  __shared__ f16 As[64 * 64];
  __shared__ f16 Bs[128 * 64];
  int tid = threadIdx.x;
  int w = tid >> 6, lane = tid & 63;
  int g = lane >> 4, c = lane & 15;
  int wr = w >> 1, wc = w & 1;
  int m0 = blockIdx.x * 64, n0 = blockIdx.y * 128;
  f32x4 acc[2][4] = {};

  for (int kt = 0; kt < K; kt += 64) {
#pragma unroll
    for (int i = 0; i < 2; ++i) {
      int seg = w * 2 + i;
      int p = seg * 1024 + lane * 16;
      int row = p >> 7;
      int colb = (p & 127) ^ ((row & 7) << 4);
      int ae = kt + (colb >> 1);
      gload_lds16(A + (size_t)permrow(m0 + row) * K + ae, &As[seg * 512]);
    }
#pragma unroll
    for (int i = 0; i < 4; ++i) {
      int seg = w * 4 + i;
      int p = seg * 1024 + lane * 16;
      int row = p >> 7;
      int colb = (p & 127) ^ ((row & 7) << 4);
      int ae = kt + (colb >> 1);
      gload_lds16(BT + (size_t)(n0 + row) * K + ae, &Bs[seg * 512]);
    }
    __syncthreads();
    f16x8 af[2][2], bf[4][2];
#pragma unroll
    for (int m = 0; m < 2; ++m) {
#pragma unroll
      for (int kk = 0; kk < 2; ++kk) {
        int row = wr * 32 + m * 16 + c;
        int tb = (row * 128 + kk * 64 + g * 16) ^ ((row & 7) << 4);
        af[m][kk] = *(const f16x8*)((const char*)As + tb);
      }
    }
#pragma unroll
    for (int n = 0; n < 4; ++n) {
#pragma unroll
      for (int kk = 0; kk < 2; ++kk) {
        int row = wc * 64 + n * 16 + c;
        int tb = (row * 128 + kk * 64 + g * 16) ^ ((row & 7) << 4);
        bf[n][kk] = *(const f16x8*)((const char*)Bs + tb);
      }
    }
    __builtin_amdgcn_s_setprio(1);
#pragma unroll
    for (int m = 0; m < 2; ++m)
#pragma unroll
      for (int n = 0; n < 4; ++n)
#pragma unroll
        for (int kk = 0; kk < 2; ++kk)
          acc[m][n] = __builtin_amdgcn_mfma_f32_16x16x32_f16(af[m][kk], bf[n][kk], acc[m][n], 0, 0, 0);
    __builtin_amdgcn_s_setprio(0);
    __syncthreads();
  }

  int rb = m0 + wr * 32;
  int cb = n0 + wc * 64;
#pragma unroll
  for (int m = 0; m < 2; ++m) {
    int row0 = rb + m * 16 + 4 * g;
#pragma unroll
    for (int n = 0; n < 4; ++n) {
      int col = cb + n * 16 + c;
      float bv = bias[col];
#pragma unroll
      for (int r = 0; r < 4; ++r) O[(size_t)(row0 + r) * N + col] = acc[m][n][r] + bv;
    }
  }
}

// ---------------- causal flash attention v8: 64 q-rows per wave (LDS-ratio x2) ----------------
// Block = 2 waves (128 thr): wave = kv-parity only. Each wave computes the FULL 64-row
// chunk against its parity's kv-tiles with TWO Q B-operands (q-cols 0..31 / 32..63);
// kf/vf LDS reads are shared by both halves -> LDS reads per FLOP halve (ratio 32->64).
// Same chunk map / parity flash-merge / staging swizzle as v7. ~225 VGPR peak, no spill.
#define THR2 11.5f  // defer-max threshold, log2 domain
__global__ __launch_bounds__(128, 1) void attn_kernel(const f16* __restrict__ Q,
                                                      const f16* __restrict__ K,
                                                      const f16* __restrict__ VT,
                                                      f16* __restrict__ AO) {
  __shared__ __attribute__((aligned(16))) f16 Ksh[2][2][64 * 64];  // [buf][par] 32 KB
  __shared__ __attribute__((aligned(16))) f16 Vsh[2][2][64 * 64];  // 32 KB
  const int BUFO = 2 * 64 * 64;  // f16 elems between buf0/buf1
  int tid = threadIdx.x;
  int par = tid >> 6, lane = tid & 63;
  int c = lane & 31, hi = lane >> 5;
  int blk = blockIdx.x;
  int bh = blk & 31;        // low bits -> head pinned per XCD
  int uu = blk >> 5;
  int cb = 31 - uu;         // big chunks first -> backfill-friendly schedule
  int b = bh >> 4, h = bh & 15;
  int q0 = cb * 64;
  const int NT = cb + 1;
  const size_t brow = (size_t)b * SEQ;
  const int hcol = h * 64;

  // staging geometry: wave par stages FULL 64-row tiles (8 K-loads + 8 V-loads)
  int sr = lane >> 3;
  int seo = ((lane & 7) ^ sr) << 3;
  const f16* Kgb = K + (size_t)(brow + sr) * D_MODEL + hcol + seo;   // + kv*D_MODEL
  const f16* Vgb = VT + ((size_t)bh * 64 + sr) * SEQ + seo;          // + kv
  f16* Kshf = &Ksh[0][0][0];
  f16* Vshf = &Vsh[0][0][0];
  f16* KshW = Kshf + par * 4096;
  f16* VshW = Vshf + par * 4096;

  // Q B-fragments for both q-halves, pre-scaled by log2e
  const f16 LOG2E = (f16)1.44269504f;
  f16x8 qfA[4], qfB[4];
  const f16* QpA = Q + (size_t)(brow + q0 + c) * D_MODEL + hcol + 8 * hi;
  const f16* QpB = Q + (size_t)(brow + q0 + 32 + c) * D_MODEL + hcol + 8 * hi;
#pragma unroll
  for (int kk = 0; kk < 4; ++kk) {
    qfA[kk] = *(const f16x8*)(QpA + 16 * kk);
    qfB[kk] = *(const f16x8*)(QpB + 16 * kk);
#pragma unroll
    for (int j = 0; j < 8; ++j) {
      qfA[kk][j] = (f16)(qfA[kk][j] * LOG2E);
      qfB[kk][j] = (f16)(qfB[kk][j] * LOG2E);
    }
  }

  float mA = -1e30f, lA = 0.f, mB = -1e30f, lB = 0.f;
  f32x16 oa0 = {}, oa1 = {}, ob0 = {}, ob1 = {};

  // prologue: stage tile par into buf 0 (if it exists)
  if (par < NT) {
    int kv = par * 64;
#pragma unroll
    for (int j = 0; j < 8; ++j) {
      gload_lds16(Kgb + (size_t)(kv + j * 8) * D_MODEL, KshW + (j * 8) * 64);
      gload_lds16(Vgb + (size_t)(j * 8) * SEQ + kv, VshW + (j * 8) * 64);
    }
  }
  __syncthreads();

  int rsw = (c & 7) << 4;
  int cur = 0;
  const int U = (NT + 1) >> 1;
  for (int u = 0; u < U; ++u) {
    int tpre = 2 * u + 2 + par;
    if (tpre < NT) {
      int kv = tpre * 64;
      f16* kd = KshW + (cur ^ 1) * BUFO;
      f16* vd = VshW + (cur ^ 1) * BUFO;
#pragma unroll
      for (int j = 0; j < 8; ++j) {
        gload_lds16(Kgb + (size_t)(kv + j * 8) * D_MODEL, kd + (j * 8) * 64);
        gload_lds16(Vgb + (size_t)(j * 8) * SEQ + kv, vd + (j * 8) * 64);
      }
    }
    int t = 2 * u + par;
    if (t < NT) {
      const char* Kb = (const char*)(Kshf + cur * BUFO + par * 4096);
      const char* Vb = (const char*)(Vshf + cur * BUFO + par * 4096);
      // ---- QK^T swapped, both q-halves share kf ----
      f16x8 kf[2][4];
#pragma unroll
      for (int ks = 0; ks < 2; ++ks)
#pragma unroll
        for (int kk = 0; kk < 4; ++kk)
          kf[ks][kk] = *(const f16x8*)(Kb + (((ks * 32 + c) * 128 + 32 * kk + 16 * hi) ^ rsw));
      f32x16 sa0 = {}, sa1 = {}, sb0 = {}, sb1 = {};
      __builtin_amdgcn_s_setprio(1);
#pragma unroll
      for (int kk = 0; kk < 4; ++kk) {
        sa0 = __builtin_amdgcn_mfma_f32_32x32x16_f16(kf[0][kk], qfA[kk], sa0, 0, 0, 0);
        sa1 = __builtin_amdgcn_mfma_f32_32x32x16_f16(kf[1][kk], qfA[kk], sa1, 0, 0, 0);
        sb0 = __builtin_amdgcn_mfma_f32_32x32x16_f16(kf[0][kk], qfB[kk], sb0, 0, 0, 0);
        sb1 = __builtin_amdgcn_mfma_f32_32x32x16_f16(kf[1][kk], qfB[kk], sb1, 0, 0, 0);
      }
      __builtin_amdgcn_s_setprio(0);
      // hoist V reads (shared by both halves' PV)
      f16x8 vf[2][4];
#pragma unroll
      for (int dt = 0; dt < 2; ++dt)
#pragma unroll
        for (int kk = 0; kk < 4; ++kk)
          vf[dt][kk] = *(const f16x8*)(Vb + (((dt * 32 + c) * 128 + 32 * kk + 16 * hi) ^ rsw));
      // ---- causal mask (diagonal tile only); kv = 64t + 32ks + (r&3)+8(r>>2)+4hi ----
      if (t == NT - 1) {
        int qA = q0 + c, qB = q0 + 32 + c;
        int kvb = t * 64 + 4 * hi;
#pragma unroll
        for (int r = 0; r < 16; ++r) {
          int kv = kvb + (r & 3) + 8 * (r >> 2);
          if (kv > qA) sa0[r] = -1e30f;
          if (kv + 32 > qA) sa1[r] = -1e30f;
          if (kv > qB) sb0[r] = -1e30f;
          if (kv + 32 > qB) sb1[r] = -1e30f;
        }
      }
      // ---- online softmax, half A ----
      {
        float t8[8];
#pragma unroll
        for (int r = 0; r < 8; ++r)
          t8[r] = fmaxf(fmaxf(sa0[r], sa0[r + 8]), fmaxf(sa1[r], sa1[r + 8]));
        float pm = fmaxf(fmaxf(fmaxf(t8[0], t8[1]), fmaxf(t8[2], t8[3])),
                         fmaxf(fmaxf(t8[4], t8[5]), fmaxf(t8[6], t8[7])));
        float mx = fmaxf(pm, __shfl_xor(pm, 32));
        if (__any(mx > mA + THR2)) {
          float mnew = fmaxf(mA, mx);
          float corr = __builtin_amdgcn_exp2f(mA - mnew);
          lA *= corr;
#pragma unroll
          for (int r = 0; r < 16; ++r) { oa0[r] *= corr; oa1[r] *= corr; }
          mA = mnew;
        }
        float ts[16];
#pragma unroll
        for (int r = 0; r < 16; ++r) {
          float p0 = __builtin_amdgcn_exp2f(sa0[r] - mA);
          float p1 = __builtin_amdgcn_exp2f(sa1[r] - mA);
          sa0[r] = p0; sa1[r] = p1;
          ts[r] = p0 + p1;
        }
#pragma unroll
        for (int st = 8; st > 0; st >>= 1)
#pragma unroll
          for (int r = 0; r < st; ++r) ts[r] += ts[r + st];
        lA += ts[0];
      }
      // ---- online softmax, half B ----
      {
        float t8[8];
#pragma unroll
        for (int r = 0; r < 8; ++r)
          t8[r] = fmaxf(fmaxf(sb0[r], sb0[r + 8]), fmaxf(sb1[r], sb1[r + 8]));
        float pm = fmaxf(fmaxf(fmaxf(t8[0], t8[1]), fmaxf(t8[2], t8[3])),
                         fmaxf(fmaxf(t8[4], t8[5]), fmaxf(t8[6], t8[7])));
        float mx = fmaxf(pm, __shfl_xor(pm, 32));
        if (__any(mx > mB + THR2)) {
          float mnew = fmaxf(mB, mx);
          float corr = __builtin_amdgcn_exp2f(mB - mnew);
          lB *= corr;
#pragma unroll
          for (int r = 0; r < 16; ++r) { ob0[r] *= corr; ob1[r] *= corr; }
          mB = mnew;
        }
        float ts[16];
#pragma unroll
        for (int r = 0; r < 16; ++r) {
          float p0 = __builtin_amdgcn_exp2f(sb0[r] - mB);
          float p1 = __builtin_amdgcn_exp2f(sb1[r] - mB);
          sb0[r] = p0; sb1[r] = p1;
          ts[r] = p0 + p1;
        }
#pragma unroll
        for (int st = 8; st > 0; st >>= 1)
#pragma unroll
          for (int r = 0; r < st; ++r) ts[r] += ts[r + st];
        lB += ts[0];
      }
      union PU { unsigned int u[4]; f16x8 v; };
      // ---- half A: pu + PV ----
      {
        PU pu[4];
#pragma unroll
        for (int kk = 0; kk < 4; ++kk) {
          int rb = 8 * (kk & 1);
          unsigned int la0, la1, lb0, lb1;
          if (kk < 2) {
            la0 = pkrtz(sa0[rb + 0], sa0[rb + 1]);
            la1 = pkrtz(sa0[rb + 2], sa0[rb + 3]);
            lb0 = pkrtz(sa0[rb + 4], sa0[rb + 5]);
            lb1 = pkrtz(sa0[rb + 6], sa0[rb + 7]);
          } else {
            la0 = pkrtz(sa1[rb + 0], sa1[rb + 1]);
            la1 = pkrtz(sa1[rb + 2], sa1[rb + 3]);
            lb0 = pkrtz(sa1[rb + 4], sa1[rb + 5]);
            lb1 = pkrtz(sa1[rb + 6], sa1[rb + 7]);
          }
          asm("v_permlane32_swap_b32 %0, %1" : "+v"(la0), "+v"(lb0));
          asm("v_permlane32_swap_b32 %0, %1" : "+v"(la1), "+v"(lb1));
          pu[kk].u[0] = la0; pu[kk].u[1] = la1; pu[kk].u[2] = lb0; pu[kk].u[3] = lb1;
        }
        __builtin_amdgcn_s_setprio(1);
#pragma unroll
        for (int kk = 0; kk < 4; ++kk) {
          oa0 = __builtin_amdgcn_mfma_f32_32x32x16_f16(vf[0][kk], pu[kk].v, oa0, 0, 0, 0);
          oa1 = __builtin_amdgcn_mfma_f32_32x32x16_f16(vf[1][kk], pu[kk].v, oa1, 0, 0, 0);
        }
        __builtin_amdgcn_s_setprio(0);
      }
      // ---- half B: pu + PV ----
      {
        PU pu[4];
#pragma unroll
        for (int kk = 0; kk < 4; ++kk) {
          int rb = 8 * (kk & 1);
          unsigned int la0, la1, lb0, lb1;
          if (kk < 2) {
            la0 = pkrtz(sb0[rb + 0], sb0[rb + 1]);
            la1 = pkrtz(sb0[rb + 2], sb0[rb + 3]);
            lb0 = pkrtz(sb0[rb + 4], sb0[rb + 5]);
            lb1 = pkrtz(sb0[rb + 6], sb0[rb + 7]);
          } else {
            la0 = pkrtz(sb1[rb + 0], sb1[rb + 1]);
            la1 = pkrtz(sb1[rb + 2], sb1[rb + 3]);
            lb0 = pkrtz(sb1[rb + 4], sb1[rb + 5]);
            lb1 = pkrtz(sb1[rb + 6], sb1[rb + 7]);
          }
          asm("v_permlane32_swap_b32 %0, %1" : "+v"(la0), "+v"(lb0));
          asm("v_permlane32_swap_b32 %0, %1" : "+v"(la1), "+v"(lb1));
          pu[kk].u[0] = la0; pu[kk].u[1] = la1; pu[kk].u[2] = lb0; pu[kk].u[3] = lb1;
        }
        __builtin_amdgcn_s_setprio(1);
#pragma unroll
        for (int kk = 0; kk < 4; ++kk) {
          ob0 = __builtin_amdgcn_mfma_f32_32x32x16_f16(vf[0][kk], pu[kk].v, ob0, 0, 0, 0);
          ob1 = __builtin_amdgcn_mfma_f32_32x32x16_f16(vf[1][kk], pu[kk].v, ob1, 0, 0, 0);
        }
        __builtin_amdgcn_s_setprio(0);
      }
    }
    __syncthreads();
    cur ^= 1;
  }

  // ---- flash merge of parity partials (exact): par1 publishes, par0 combines ----
  float* sc = (float*)Kshf;  // K LDS dead; 128 entries x 34 f32 = 17.4 KB (< 32 KB)
  int mbA = lane * 34;
  int mbB = (64 + lane) * 34;
  if (par == 1) {
    sc[mbA] = mA; sc[mbA + 1] = lA;
#pragma unroll
    for (int r = 0; r < 16; ++r) { sc[mbA + 2 + r] = oa0[r]; sc[mbA + 18 + r] = oa1[r]; }
    sc[mbB] = mB; sc[mbB + 1] = lB;
#pragma unroll
    for (int r = 0; r < 16; ++r) { sc[mbB + 2 + r] = ob0[r]; sc[mbB + 18 + r] = ob1[r]; }
  }
  __syncthreads();
  if (par == 0) {
    // half A
    {
      float m1 = sc[mbA], l1 = sc[mbA + 1];
      float mm = fmaxf(mA, m1);
      float c0 = __builtin_amdgcn_exp2f(mA - mm);
      float c1 = __builtin_amdgcn_exp2f(m1 - mm);
      float l = lA * c0 + l1 * c1;
#pragma unroll
      for (int r = 0; r < 16; ++r) {
        oa0[r] = oa0[r] * c0 + sc[mbA + 2 + r] * c1;
        oa1[r] = oa1[r] * c0 + sc[mbA + 18 + r] * c1;
      }
      float lt = l + __shfl_xor(l, 32);
      float linv = 1.0f / lt;
      f16* aoq = AO + ((size_t)bh * SEQ + q0 + c) * 64 + 4 * hi;
#pragma unroll
      for (int rq = 0; rq < 4; ++rq) {
        f16x4 h0, h1;
#pragma unroll
        for (int r = 0; r < 4; ++r) {
          h0[r] = (f16)(oa0[4 * rq + r] * linv);
          h1[r] = (f16)(oa1[4 * rq + r] * linv);
        }
        *(f16x4*)(aoq + 8 * rq) = h0;
        *(f16x4*)(aoq + 32 + 8 * rq) = h1;
      }
    }
    // half B
    {
      float m1 = sc[mbB], l1 = sc[mbB + 1];
      float mm = fmaxf(mB, m1);
      float c0 = __builtin_amdgcn_exp2f(mB - mm);
      float c1 = __builtin_amdgcn_exp2f(m1 - mm);
      float l = lB * c0 + l1 * c1;
#pragma unroll
      for (int r = 0; r < 16; ++r) {
        ob0[r] = ob0[r] * c0 + sc[mbB + 2 + r] * c1;
        ob1[r] = ob1[r] * c0 + sc[mbB + 18 + r] * c1;
      }
      float lt = l + __shfl_xor(l, 32);
      float linv = 1.0f / lt;
      f16* aoq = AO + ((size_t)bh * SEQ + q0 + 32 + c) * 64 + 4 * hi;
#pragma unroll
      for (int rq = 0; rq < 4; ++rq) {
        f16x4 h0, h1;
#pragma unroll
        for (int r = 0; r < 4; ++r) {
          h0[r] = (f16)(ob0[4 * rq + r] * linv);
          h1[r] = (f16)(ob1[4 * rq + r] * linv);
        }
        *(f16x4*)(aoq + 8 * rq) = h0;
        *(f16x4*)(aoq + 32 + 8 * rq) = h1;
      }
    }
  }
}

extern "C" void kernel_launch(void* const* d_in, const int* in_sizes, int n_in,
                              void* d_out, int out_size, void* d_ws, size_t ws_size,
                              hipStream_t stream) {
  const float* q  = (const float*)d_in[0];
  const float* k  = (const float*)d_in[1];
  const float* v  = (const float*)d_in[2];
  const float* wq = (const float*)d_in[3];
  const float* bq = (const float*)d_in[4];
  const float* wk = (const float*)d_in[5];
  const float* bk = (const float*)d_in[6];
  const float* wv = (const float*)d_in[7];
  const float* bv = (const float*)d_in[8];
  const float* wo = (const float*)d_in[9];
  const float* bo = (const float*)d_in[10];

  const size_t TEN = (size_t)MTOT * D_MODEL;
  const size_t WEL = (size_t)D_MODEL * D_MODEL;
  f16* ws  = (f16*)d_ws;
  f16* q16 = ws;
  f16* k16 = q16 + TEN;
  f16* v16 = k16 + TEN;
  f16* wT  = v16 + TEN;
  f16* Q16 = wT + 4 * WEL;
  f16* K16 = Q16 + TEN;
  f16* VT16 = K16 + TEN;
  f16* AO  = q16;  // alias: q16 dead after QKV projection

  static bool attr_set = false;
  if (!attr_set) {
    hipFuncSetAttribute(reinterpret_cast<const void*>(&gemm_qkv),
                        hipFuncAttributeMaxDynamicSharedMemorySize, 131072);
    attr_set = true;
  }

  cvt_all<<<7168, 256, 0, stream>>>(q, k, v, wq, wk, wv, wo, q16, wT);
  gemm_qkv<<<dim3(16, 4, 3), 512, 131072, stream>>>(q16, k16, v16, wT, bq, bk, bv, Q16, K16, VT16);
  attn_kernel<<<1024, 128, 0, stream>>>(Q16, K16, VT16, AO);
  gemm_out<<<dim3(64, 8), 256, 0, stream>>>(AO, wT + 3 * WEL, bo, (float*)d_out);
}

// Round 7
// 108.436 us; speedup vs baseline: 1.2557x; 1.1427x over previous
//
#include <hip/hip_runtime.h>

typedef __fp16 f16;
typedef __fp16 f16x8 __attribute__((ext_vector_type(8)));
typedef __fp16 f16x4 __attribute__((ext_vector_type(4)));
typedef __fp16 f16x2 __attribute__((ext_vector_type(2)));
typedef float f32x4 __attribute__((ext_vector_type(4)));
typedef float f32x16 __attribute__((ext_vector_type(16)));

#define D_MODEL 1024
#define SEQ 2048
#define NH 16
#define MTOT 4096  // B*S

typedef const __attribute__((address_space(1))) unsigned int* gp1_t;
typedef __attribute__((address_space(3))) unsigned int* lp3_t;

__device__ __forceinline__ void gload_lds16(const void* g, void* l) {
  __builtin_amdgcn_global_load_lds((gp1_t)g, (lp3_t)l, 16, 0, 0);
}

// Z-row r' -> AO superrow j (the reference's transpose/view bug, closed form)
__device__ __forceinline__ int permrow(int r) {
  int bp = r >> 11, u = (r >> 7) & 15, t = r & 127;
  int g16 = (bp << 4) | u;
  return ((((g16 & 1) << 4) | (g16 >> 1)) << 7) + t;  // (b*16+h)*128 + t
}

__device__ __forceinline__ unsigned int pkrtz(float a, float b) {
  union { f16x2 h; unsigned int u; } z;
  z.h = __builtin_amdgcn_cvt_pkrtz(a, b);
  return z.u;
}

// ---------------- merged converts: qkv fp32->f16 (blocks 0..6143), wT (blocks 6144..7167) ----------------
__global__ __launch_bounds__(256) void cvt_all(const float* __restrict__ q,
                                               const float* __restrict__ k,
                                               const float* __restrict__ v,
                                               const float* __restrict__ wq,
                                               const float* __restrict__ wk,
                                               const float* __restrict__ wv,
                                               const float* __restrict__ wo,
                                               f16* __restrict__ qkv16,
                                               f16* __restrict__ wT) {
  __shared__ float tl[64][65];
  int bid = blockIdx.x, tid = threadIdx.x;
  if (bid < 6144) {
    int i = bid * 256 + tid;
    const int NT = (MTOT * D_MODEL) / 8;
    const float* src;
    int t;
    if (i < NT) { src = q; t = i; }
    else if (i < 2 * NT) { src = k; t = i - NT; }
    else { src = v; t = i - 2 * NT; }
    const float4* s4 = (const float4*)src;
    float4 a = s4[2 * t], b = s4[2 * t + 1];
    f16x8 h;
    h[0] = (f16)a.x; h[1] = (f16)a.y; h[2] = (f16)a.z; h[3] = (f16)a.w;
    h[4] = (f16)b.x; h[5] = (f16)b.y; h[6] = (f16)b.z; h[7] = (f16)b.w;
    *(f16x8*)(qkv16 + (size_t)i * 8) = h;
  } else {
    int bb = bid - 6144;
    int mat = bb >> 8, tile = bb & 255;
    int tk = (tile >> 4) << 6, tn = (tile & 15) << 6;
    const float* W = mat == 0 ? wq : mat == 1 ? wk : mat == 2 ? wv : wo;
    int rr = tid >> 4, c4 = (tid & 15) << 2;
#pragma unroll
    for (int it = 0; it < 4; ++it) {
      const float* p = W + (size_t)(tk + it * 16 + rr) * D_MODEL + tn + c4;
      float4 val = *(const float4*)p;
      tl[it * 16 + rr][c4 + 0] = val.x;
      tl[it * 16 + rr][c4 + 1] = val.y;
      tl[it * 16 + rr][c4 + 2] = val.z;
      tl[it * 16 + rr][c4 + 3] = val.w;
    }
    __syncthreads();
    int n = tid & 63, kseg = (tid >> 6) << 4;
    f16x8 lo, hi;
#pragma unroll
    for (int j = 0; j < 8; ++j) lo[j] = (f16)tl[kseg + j][n];
#pragma unroll
    for (int j = 0; j < 8; ++j) hi[j] = (f16)tl[kseg + 8 + j][n];
    f16* d = wT + (size_t)mat * (D_MODEL * D_MODEL) + (size_t)(tn + n) * D_MODEL + tk + kseg;
    *(f16x8*)d = lo;
    *(f16x8*)(d + 8) = hi;
  }
}

// ---------------- fused QKV projection GEMM v5: 128x128 tile, BK=32, 4-slot ring,
// 3-deep prefetch, counted vmcnt (v3's pipeline) at FULL CU coverage.
// 4 waves of 64x64 (256 thr), LDS 64 KB -> 2 blocks/CU resident; grid (32,8,3)=768
// = 256 CUs x (2 resident + 1 backfill). Same verified swizzle/staging math as v3.
#define SLOT_Q 8192  // 16 KB in f16
__global__ __launch_bounds__(256, 2) void gemm_qkv(const f16* __restrict__ q16,
                                                   const f16* __restrict__ k16,
                                                   const f16* __restrict__ v16,
                                                   const f16* __restrict__ wT,
                                                   const float* __restrict__ bq,
                                                   const float* __restrict__ bk,
                                                   const float* __restrict__ bv,
                                                   f16* __restrict__ Q16,
                                                   f16* __restrict__ K16,
                                                   f16* __restrict__ VT16) {
  extern __shared__ __attribute__((aligned(16))) f16 sm[];  // 4 x 16 KB ring
  const int K = D_MODEL, N = D_MODEL;
  const size_t WEL = (size_t)D_MODEL * D_MODEL;
  int z = blockIdx.z;
  const f16* A = z == 0 ? q16 : z == 1 ? k16 : v16;
  const f16* BT = wT + (size_t)z * WEL;
  const float* bias = z == 0 ? bq : z == 1 ? bk : bv;

  int tid = threadIdx.x;
  int w = tid >> 6, lane = tid & 63;
  int g = lane >> 4, c = lane & 15;
  int wr = w >> 1, wc = w & 1;
  int m0 = blockIdx.x * 128, n0 = blockIdx.y * 128;
  f32x4 acc[4][4] = {};

  // staging geometry (v3-verified): wave w stages rows w*32..w*32+31 of A and B
  // (2 gloads each); inverse-swizzled per-lane source, linear LDS dest.
  int sl0 = lane >> 3, s = lane & 7;
  int u = s ^ sl0;
  int rlow = u >> 2, gsl = u & 3;
  const f16* Agp = A + (size_t)(m0 + w * 32 + 2 * sl0 + rlow) * K + gsl * 8;
  const f16* Bgp = BT + (size_t)(n0 + w * 32 + 2 * sl0 + rlow) * K + gsl * 8;

#define STAGE_Q(tt, bi)                                                      \
  {                                                                          \
    f16* dA = sm + (bi)*SLOT_Q + w * 1024;                                   \
    f16* dB = sm + (bi)*SLOT_Q + 4096 + w * 1024;                            \
    const f16* sa = Agp + (size_t)(tt)*32;                                   \
    const f16* sb = Bgp + (size_t)(tt)*32;                                   \
    gload_lds16(sa, dA);                                                     \
    gload_lds16(sa + (size_t)16 * K, dA + 512);                              \
    gload_lds16(sb, dB);                                                     \
    gload_lds16(sb + (size_t)16 * K, dB + 512);                              \
  }

  // prologue: stage tiles 0,1,2 into slots 0,1,2 (12 loads/thread in flight)
  STAGE_Q(0, 0)
  STAGE_Q(1, 1)
  STAGE_Q(2, 2)

  const int NKT = K / 32;  // 32
  for (int t = 0; t < NKT; ++t) {
    if (t < NKT - 2) asm volatile("s_waitcnt vmcnt(8)" ::: "memory");
    else if (t == NKT - 2) asm volatile("s_waitcnt vmcnt(4)" ::: "memory");
    else asm volatile("s_waitcnt vmcnt(0)" ::: "memory");
    __builtin_amdgcn_sched_barrier(0);
    __builtin_amdgcn_s_barrier();  // tile t resident; reads of slot (t-1)&3 drained
    __builtin_amdgcn_sched_barrier(0);
    if (t + 3 < NKT) STAGE_Q(t + 3, (t + 3) & 3)

    const char* Ac = (const char*)(sm + (t & 3) * SLOT_Q);
    const char* Bc = Ac + 8192;  // bytes
    f16x8 af[4], bf[4];
#pragma unroll
    for (int mi = 0; mi < 4; ++mi) {
      int row = wr * 64 + mi * 16 + c;
      int tb = (row >> 1) * 128 + (((((row & 1) << 2) | g) ^ ((row >> 1) & 7)) << 4);
      af[mi] = *(const f16x8*)(Ac + tb);
    }
#pragma unroll
    for (int ni = 0; ni < 4; ++ni) {
      int row = wc * 64 + ni * 16 + c;
      int tb = (row >> 1) * 128 + (((((row & 1) << 2) | g) ^ ((row >> 1) & 7)) << 4);
      bf[ni] = *(const f16x8*)(Bc + tb);
    }
    asm volatile("s_waitcnt lgkmcnt(0)" ::: "memory");
    __builtin_amdgcn_sched_barrier(0);
    __builtin_amdgcn_s_setprio(1);
#pragma unroll
    for (int mi = 0; mi < 4; ++mi)
#pragma unroll
      for (int ni = 0; ni < 4; ++ni)
        acc[mi][ni] = __builtin_amdgcn_mfma_f32_16x16x32_f16(af[mi], bf[ni], acc[mi][ni], 0, 0, 0);
    __builtin_amdgcn_s_setprio(0);
  }

  int rb = m0 + wr * 64;
  int cb = n0 + wc * 64;
  if (z < 2) {
    f16* O = z == 0 ? Q16 : K16;
#pragma unroll
    for (int m = 0; m < 4; ++m) {
      int row0 = rb + m * 16 + 4 * g;
#pragma unroll
      for (int n = 0; n < 4; ++n) {
        int col = cb + n * 16 + c;
        float bv2 = bias[col];
#pragma unroll
        for (int r = 0; r < 4; ++r) O[(size_t)(row0 + r) * N + col] = (f16)(acc[m][n][r] + bv2);
      }
    }
  } else {
    f16* O = VT16;
#pragma unroll
    for (int m = 0; m < 4; ++m) {
      int s0f = rb + m * 16 + 4 * g;
      int bb = s0f >> 11, ss = s0f & (SEQ - 1);
#pragma unroll
      for (int n = 0; n < 4; ++n) {
        int col = cb + n * 16 + c;
        float bv2 = bias[col];
        f16x4 hv;
#pragma unroll
        for (int r = 0; r < 4; ++r) hv[r] = (f16)(acc[m][n][r] + bv2);
        *(f16x4*)(O + ((size_t)(bb * NH + (col >> 6)) * 64 + (col & 63)) * SEQ + ss) = hv;
      }
    }
  }
}

// ---------------- O-projection GEMM: 64x128 tiles, permuted A rows, f32 out ----------------
__global__ __launch_bounds__(256, 2) void gemm_out(const f16* __restrict__ A,
                                                   const f16* __restrict__ BT,
                                                   const float* __restrict__ bias,
                                                   float* __restrict__ O) {
  const int K = D_MODEL, N = D_MODEL;
  __shared__ f16 As[64 * 64];
  __shared__ f16 Bs[128 * 64];
  int tid = threadIdx.x;
  int w = tid >> 6, lane = tid & 63;
  int g = lane >> 4, c = lane & 15;
  int wr = w >> 1, wc = w & 1;
  int m0 = blockIdx.x * 64, n0 = blockIdx.y * 128;
  f32x4 acc[2][4] = {};

  for (int kt = 0; kt < K; kt += 64) {
#pragma unroll
    for (int i = 0; i < 2; ++i) {
      int seg = w * 2 + i;
      int p = seg * 1024 + lane * 16;
      int row = p >> 7;
      int colb = (p & 127) ^ ((row & 7) << 4);
      int ae = kt + (colb >> 1);
      gload_lds16(A + (size_t)permrow(m0 + row) * K + ae, &As[seg * 512]);
    }
#pragma unroll
    for (int i = 0; i < 4; ++i) {
      int seg = w * 4 + i;
      int p = seg * 1024 + lane * 16;
      int row = p >> 7;
      int colb = (p & 127) ^ ((row & 7) << 4);
      int ae = kt + (colb >> 1);
      gload_lds16(BT + (size_t)(n0 + row) * K + ae, &Bs[seg * 512]);
    }
    __syncthreads();
    f16x8 af[2][2], bf[4][2];
#pragma unroll
    for (int m = 0; m < 2; ++m) {
#pragma unroll
      for (int kk = 0; kk < 2; ++kk) {
        int row = wr * 32 + m * 16 + c;
        int tb = (row * 128 + kk * 64 + g * 16) ^ ((row & 7) << 4);
        af[m][kk] = *(const f16x8*)((const char*)As + tb);
      }
    }
#pragma unroll
    for (int n = 0; n < 4; ++n) {
#pragma unroll
      for (int kk = 0; kk < 2; ++kk) {
        int row = wc * 64 + n * 16 + c;
        int tb = (row * 128 + kk * 64 + g * 16) ^ ((row & 7) << 4);
        bf[n][kk] = *(const f16x8*)((const char*)Bs + tb);
      }
    }
    __builtin_amdgcn_s_setprio(1);
#pragma unroll
    for (int m = 0; m < 2; ++m)
#pragma unroll
      for (int n = 0; n < 4; ++n)
#pragma unroll
        for (int kk = 0; kk < 2; ++kk)
          acc[m][n] = __builtin_amdgcn_mfma_f32_16x16x32_f16(af[m][kk], bf[n][kk], acc[m][n], 0, 0, 0);
    __builtin_amdgcn_s_setprio(0);
    __syncthreads();
  }

  int rb = m0 + wr * 32;
  int cb = n0 + wc * 64;
#pragma unroll
  for (int m = 0; m < 2; ++m) {
    int row0 = rb + m * 16 + 4 * g;
#pragma unroll
    for (int n = 0; n < 4; ++n) {
      int col = cb + n * 16 + c;
      float bv = bias[col];
#pragma unroll
      for (int r = 0; r < 4; ++r) O[(size_t)(row0 + r) * N + col] = acc[m][n][r] + bv;
    }
  }
}

// ---------------- causal flash attention v7 (reverted, verified ~41 us):
// kv-parity split + flash merge ----------------
#define THR2 11.5f  // defer-max threshold, log2 domain
__global__ __launch_bounds__(256, 2) void attn_kernel(const f16* __restrict__ Q,
                                                      const f16* __restrict__ K,
                                                      const f16* __restrict__ VT,
                                                      f16* __restrict__ AO) {
  __shared__ __attribute__((aligned(16))) f16 Ksh[2][2][64 * 64];  // [buf][par] 32 KB
  __shared__ __attribute__((aligned(16))) f16 Vsh[2][2][64 * 64];  // 32 KB
  const int BUFO = 2 * 64 * 64;  // f16 elems between buf0/buf1
  int tid = threadIdx.x;
  int w = tid >> 6, lane = tid & 63;
  int c = lane & 31, hi = lane >> 5;
  int qh = w & 1, par = w >> 1;
  int blk = blockIdx.x;
  int bh = blk & 31;        // low bits -> head pinned per XCD
  int uu = blk >> 5;
  int cb = 31 - uu;         // big chunks first -> backfill-friendly schedule
  int b = bh >> 4, h = bh & 15;
  int q0 = cb * 64 + qh * 32;
  const int NT = cb + 1;
  const size_t brow = (size_t)b * SEQ;
  const int hcol = h * 64;

  // staging geometry: wave (qh,par) stages tile (t0+par), rows qh*32 + j*8 + (lane>>3)
  int sr = lane >> 3;
  int seo = ((lane & 7) ^ sr) << 3;
  const f16* Kgb = K + (size_t)(brow + qh * 32 + sr) * D_MODEL + hcol + seo;  // + kv*D_MODEL
  const f16* Vgb = VT + ((size_t)bh * 64 + qh * 32 + sr) * SEQ + seo;         // + kv
  f16* Kshf = &Ksh[0][0][0];
  f16* Vshf = &Vsh[0][0][0];
  f16* KshW = Kshf + par * 4096 + qh * 32 * 64;
  f16* VshW = Vshf + par * 4096 + qh * 32 * 64;

  // Q B-fragments (col=q-row=c, k = 16*kk + 8*hi + j), pre-scaled by log2e
  const f16 LOG2E = (f16)1.44269504f;
  f16x8 qf[4];
  const f16* Qp = Q + (size_t)(brow + q0 + c) * D_MODEL + hcol + 8 * hi;
#pragma unroll
  for (int kk = 0; kk < 4; ++kk) {
    qf[kk] = *(const f16x8*)(Qp + 16 * kk);
#pragma unroll
    for (int j = 0; j < 8; ++j) qf[kk][j] = (f16)(qf[kk][j] * LOG2E);
  }

  float m_st = -1e30f, l_st = 0.f;
  f32x16 o0 = {}, o1 = {};  // O^T accumulators, d-tiles 0..31 / 32..63; col=q per lane

  // prologue: stage pair {0,1} into buf 0 (this wave: tile par, if it exists)
  if (par < NT) {
    int kv = par * 64;
#pragma unroll
    for (int j = 0; j < 4; ++j) {
      gload_lds16(Kgb + (size_t)(kv + j * 8) * D_MODEL, KshW + (j * 8) * 64);
      gload_lds16(Vgb + (size_t)(j * 8) * SEQ + kv, VshW + (j * 8) * 64);
    }
  }
  __syncthreads();

  int rsw = (c & 7) << 4;
  int cur = 0;
  const int U = (NT + 1) >> 1;
  for (int u = 0; u < U; ++u) {
    int tpre = 2 * u + 2 + par;
    if (tpre < NT) {
      int kv = tpre * 64;
      f16* kd = KshW + (cur ^ 1) * BUFO;
      f16* vd = VshW + (cur ^ 1) * BUFO;
#pragma unroll
      for (int j = 0; j < 4; ++j) {
        gload_lds16(Kgb + (size_t)(kv + j * 8) * D_MODEL, kd + (j * 8) * 64);
        gload_lds16(Vgb + (size_t)(j * 8) * SEQ + kv, vd + (j * 8) * 64);
      }
    }
    int t = 2 * u + par;
    if (t < NT) {
      const char* Kb = (const char*)(Kshf + cur * BUFO + par * 4096);
      const char* Vb = (const char*)(Vshf + cur * BUFO + par * 4096);
      // ---- QK^T swapped: S^T[kv][q] = K . Q^T ----
      f16x8 kf[2][4];
#pragma unroll
      for (int ks = 0; ks < 2; ++ks)
#pragma unroll
        for (int kk = 0; kk < 4; ++kk)
          kf[ks][kk] = *(const f16x8*)(Kb + (((ks * 32 + c) * 128 + 32 * kk + 16 * hi) ^ rsw));
      f32x16 s0 = {}, s1 = {};
      __builtin_amdgcn_s_setprio(1);
#pragma unroll
      for (int kk = 0; kk < 4; ++kk) {
        s0 = __builtin_amdgcn_mfma_f32_32x32x16_f16(kf[0][kk], qf[kk], s0, 0, 0, 0);
        s1 = __builtin_amdgcn_mfma_f32_32x32x16_f16(kf[1][kk], qf[kk], s1, 0, 0, 0);
      }
      __builtin_amdgcn_s_setprio(0);
      // hoist V reads: independent of softmax, covers ds latency under VALU
      f16x8 vf[2][4];
#pragma unroll
      for (int dt = 0; dt < 2; ++dt)
#pragma unroll
        for (int kk = 0; kk < 4; ++kk)
          vf[dt][kk] = *(const f16x8*)(Vb + (((dt * 32 + c) * 128 + 32 * kk + 16 * hi) ^ rsw));
      // ---- causal mask (diagonal tile only); kv = 64t + 32ks + (r&3)+8(r>>2)+4hi ----
      if (t == NT - 1) {
        int q = q0 + c;
        int kvb = t * 64 + 4 * hi;
#pragma unroll
        for (int r = 0; r < 16; ++r) {
          int kv = kvb + (r & 3) + 8 * (r >> 2);
          if (kv > q) s0[r] = -1e30f;
          if (kv + 32 > q) s1[r] = -1e30f;
        }
      }
      // ---- online softmax: each lane holds 32 scores of ONE q-row (other half at lane^32) ----
      float t8[8];
#pragma unroll
      for (int r = 0; r < 8; ++r)
        t8[r] = fmaxf(fmaxf(s0[r], s0[r + 8]), fmaxf(s1[r], s1[r + 8]));
      float pm = fmaxf(fmaxf(fmaxf(t8[0], t8[1]), fmaxf(t8[2], t8[3])),
                       fmaxf(fmaxf(t8[4], t8[5]), fmaxf(t8[6], t8[7])));
      float mx = fmaxf(pm, __shfl_xor(pm, 32));
      if (__any(mx > m_st + THR2)) {
        float mnew = fmaxf(m_st, mx);
        float corr = __builtin_amdgcn_exp2f(m_st - mnew);
        l_st *= corr;
#pragma unroll
        for (int r = 0; r < 16; ++r) { o0[r] *= corr; o1[r] *= corr; }
        m_st = mnew;
      }
      float ts[16];
#pragma unroll
      for (int r = 0; r < 16; ++r) {
        float p0 = __builtin_amdgcn_exp2f(s0[r] - m_st);  // <= 2^11.5, f16-safe
        float p1 = __builtin_amdgcn_exp2f(s1[r] - m_st);
        s0[r] = p0; s1[r] = p1;
        ts[r] = p0 + p1;
      }
#pragma unroll
      for (int st = 8; st > 0; st >>= 1)
#pragma unroll
        for (int r = 0; r < st; ++r) ts[r] += ts[r + st];
      l_st += ts[0];
      // ---- P -> PV B-fragments in-register (cvt_pkrtz pairs + permlane32 hi/lo swap) ----
      union PU { unsigned int u[4]; f16x8 v; };
      PU pu[4];
#pragma unroll
      for (int kk = 0; kk < 4; ++kk) {
        int rb = 8 * (kk & 1);
        unsigned int la0, la1, lb0, lb1;
        if (kk < 2) {
          la0 = pkrtz(s0[rb + 0], s0[rb + 1]);
          la1 = pkrtz(s0[rb + 2], s0[rb + 3]);
          lb0 = pkrtz(s0[rb + 4], s0[rb + 5]);
          lb1 = pkrtz(s0[rb + 6], s0[rb + 7]);
        } else {
          la0 = pkrtz(s1[rb + 0], s1[rb + 1]);
          la1 = pkrtz(s1[rb + 2], s1[rb + 3]);
          lb0 = pkrtz(s1[rb + 4], s1[rb + 5]);
          lb1 = pkrtz(s1[rb + 6], s1[rb + 7]);
        }
        asm("v_permlane32_swap_b32 %0, %1" : "+v"(la0), "+v"(lb0));
        asm("v_permlane32_swap_b32 %0, %1" : "+v"(la1), "+v"(lb1));
        pu[kk].u[0] = la0; pu[kk].u[1] = la1; pu[kk].u[2] = lb0; pu[kk].u[3] = lb1;
      }
      // ---- PV: O^T[d][q] += V^T[d][kv] * P^T[kv][q] ----
      __builtin_amdgcn_s_setprio(1);
#pragma unroll
      for (int kk = 0; kk < 4; ++kk) {
        o0 = __builtin_amdgcn_mfma_f32_32x32x16_f16(vf[0][kk], pu[kk].v, o0, 0, 0, 0);
        o1 = __builtin_amdgcn_mfma_f32_32x32x16_f16(vf[1][kk], pu[kk].v, o1, 0, 0, 0);
      }
      __builtin_amdgcn_s_setprio(0);
    }
    __syncthreads();
    cur ^= 1;
  }

  // ---- flash merge of parity partials (exact): par1 publishes, par0 combines ----
  float* sc = (float*)Kshf;  // K LDS dead after loop; 128 x 34 f32 = 17 KB
  int mb = (qh * 64 + lane) * 34;
  if (par == 1) {
    sc[mb] = m_st;
    sc[mb + 1] = l_st;
#pragma unroll
    for (int r = 0; r < 16; ++r) { sc[mb + 2 + r] = o0[r]; sc[mb + 18 + r] = o1[r]; }
  }
  __syncthreads();
  if (par == 0) {
    float m1 = sc[mb], l1 = sc[mb + 1];
    float mm = fmaxf(m_st, m1);
    float c0 = __builtin_amdgcn_exp2f(m_st - mm);
    float c1 = __builtin_amdgcn_exp2f(m1 - mm);
    float l = l_st * c0 + l1 * c1;
#pragma unroll
    for (int r = 0; r < 16; ++r) {
      o0[r] = o0[r] * c0 + sc[mb + 2 + r] * c1;
      o1[r] = o1[r] * c0 + sc[mb + 18 + r] * c1;
    }
    // combine hi/lo kv-half row sums, normalize, write AO[bh][s][64]
    float lt = l + __shfl_xor(l, 32);
    float linv = 1.0f / lt;
    f16* aoq = AO + ((size_t)bh * SEQ + q0 + c) * 64 + 4 * hi;
#pragma unroll
    for (int rq = 0; rq < 4; ++rq) {
      f16x4 h0, h1;
#pragma unroll
      for (int r = 0; r < 4; ++r) {
        h0[r] = (f16)(o0[4 * rq + r] * linv);
        h1[r] = (f16)(o1[4 * rq + r] * linv);
      }
      *(f16x4*)(aoq + 8 * rq) = h0;
      *(f16x4*)(aoq + 32 + 8 * rq) = h1;
    }
  }
}

extern "C" void kernel_launch(void* const* d_in, const int* in_sizes, int n_in,
                              void* d_out, int out_size, void* d_ws, size_t ws_size,
                              hipStream_t stream) {
  const float* q  = (const float*)d_in[0];
  const float* k  = (const float*)d_in[1];
  const float* v  = (const float*)d_in[2];
  const float* wq = (const float*)d_in[3];
  const float* bq = (const float*)d_in[4];
  const float* wk = (const float*)d_in[5];
  const float* bk = (const float*)d_in[6];
  const float* wv = (const float*)d_in[7];
  const float* bv = (const float*)d_in[8];
  const float* wo = (const float*)d_in[9];
  const float* bo = (const float*)d_in[10];

  const size_t TEN = (size_t)MTOT * D_MODEL;
  const size_t WEL = (size_t)D_MODEL * D_MODEL;
  f16* ws  = (f16*)d_ws;
  f16* q16 = ws;
  f16* k16 = q16 + TEN;
  f16* v16 = k16 + TEN;
  f16* wT  = v16 + TEN;
  f16* Q16 = wT + 4 * WEL;
  f16* K16 = Q16 + TEN;
  f16* VT16 = K16 + TEN;
  f16* AO  = q16;  // alias: q16 dead after QKV projection

  static bool attr_set = false;
  if (!attr_set) {
    hipFuncSetAttribute(reinterpret_cast<const void*>(&gemm_qkv),
                        hipFuncAttributeMaxDynamicSharedMemorySize, 65536);
    attr_set = true;
  }

  cvt_all<<<7168, 256, 0, stream>>>(q, k, v, wq, wk, wv, wo, q16, wT);
  gemm_qkv<<<dim3(32, 8, 3), 256, 65536, stream>>>(q16, k16, v16, wT, bq, bk, bv, Q16, K16, VT16);
  attn_kernel<<<1024, 256, 0, stream>>>(Q16, K16, VT16, AO);
  gemm_out<<<dim3(64, 8), 256, 0, stream>>>(AO, wT + 3 * WEL, bo, (float*)d_out);
}